// Round 1
// 277.413 us; speedup vs baseline: 1.0901x; 1.0901x over previous
//
#include <hip/hip_runtime.h>
#include <hip/hip_bf16.h>
#include <stdint.h>

#define EPSF 1e-8f

typedef __attribute__((ext_vector_type(8))) short short8;
typedef __attribute__((ext_vector_type(8))) _Float16 half8;
typedef __attribute__((ext_vector_type(4))) float floatx4;

__device__ __forceinline__ unsigned short f2h(float f) {
    _Float16 h = (_Float16)f;
    return __builtin_bit_cast(unsigned short, h);
}
__device__ __forceinline__ float h2f(unsigned short u) {
    return (float)__builtin_bit_cast(_Float16, u);
}

// ---------------- fused conversion kernel (float4-vectorized) ----------------

__global__ void prep_kernel(const float4* __restrict__ x4, ushort4* __restrict__ x16,
                            const float4* __restrict__ wi4, ushort4* __restrict__ wi16,
                            const float4* __restrict__ wo4, ushort4* __restrict__ wo16,
                            int nx4, int nw4, int nwo4) {
    int i = blockIdx.x * blockDim.x + threadIdx.x;
    float4 f; ushort4 u;
    if (i < nx4) {
        f = x4[i];
        u.x = f2h(f.x); u.y = f2h(f.y); u.z = f2h(f.z); u.w = f2h(f.w);
        x16[i] = u;
    } else if (i < nx4 + nw4) {
        int j = i - nx4;
        f = wi4[j];
        u.x = f2h(f.x); u.y = f2h(f.y); u.z = f2h(f.z); u.w = f2h(f.w);
        wi16[j] = u;
    } else if (i < nx4 + nw4 + nwo4) {
        int j = i - nx4 - nw4;
        f = wo4[j];
        u.x = f2h(f.x); u.y = f2h(f.y); u.z = f2h(f.z); u.w = f2h(f.w);
        wo16[j] = u;
    }
}

// ---------------- phase-pipelined MFMA GEMM (C = A * B^T + bias), fp16 ----------------
// T3+T4+T5 structure (counted vmcnt, never drained in main loop):
//   BM=256 x BN=128 x BK=64, 8 waves (4M x 2N), per-wave 64x64 via 16x16x32 MFMA
//   (M_rep=N_rep=4 -> 4-way LDS reuse on both operands, 16 indep acc chains).
//   3 LDS slots (48 KB each, 144 KB total): tile t computes slot t%3 while
//   tile t+2 stages into slot (t+2)%3 -> prefetch distance 2, race-free.
//   Boundary wait entering tile t: vmcnt(6) = the 6 in-flight loads of t+1.
//   2 phases per K-tile: {8x ds_read_b128, 3x global_load_lds(t+2), barrier,
//   setprio(1), 16x MFMA, setprio(0), barrier}.
// Fragment layouts (16x16x32, verified m89/m91):
//   A/B: row|col = lane&15, k = (lane>>4)*8 + i
//   C/D: col = lane&15, row = (lane>>4)*4 + reg
// LDS swizzle: chunk col c holds global 8-elem chunk c ^ (row&7) (0 conflicts,
// carried over from previous kernel; both-sides swizzle per rule 21).

__device__ __forceinline__ void gld16(const unsigned short* g, unsigned short* l) {
    __builtin_amdgcn_global_load_lds(
        (const __attribute__((address_space(1))) unsigned int*)g,
        (__attribute__((address_space(3))) unsigned int*)l, 16, 0, 0);
}

template <bool HALFOUT>
__global__ __launch_bounds__(512, 2)
void gemm8p(const unsigned short* __restrict__ Am, const unsigned short* __restrict__ Bm,
            const float* __restrict__ bias, void* __restrict__ Cv,
            int M, int N, int K) {
    constexpr int BM = 256, BN = 128, BK = 64;
    constexpr int ASZ  = BM * BK;        // 16384 fp16 (32 KB)
    constexpr int BSZ  = BN * BK;        // 8192  fp16 (16 KB)
    constexpr int SLOT = ASZ + BSZ;      // 24576 fp16 (48 KB)
    extern __shared__ unsigned short smem[];

    const int tid  = threadIdx.x;
    const int lane = tid & 63;
    const int wid  = tid >> 6;           // 0..7
    const int wr   = wid >> 1;           // 0..3: 64-row strip
    const int wc   = wid & 1;            // 0..1: 64-col strip
    const int q4   = lane >> 4;          // 0..3
    const int m16  = lane & 15;
    const int x7   = m16 & 7;

    // XCD-aware swizzle of 1D block id (grid % 8 == 0 for both GEMMs)
    const int nbx = N / BN;
    const int nwg = gridDim.x;
    const int q   = nwg >> 3;
    const int wg  = blockIdx.x;
    const int sz  = (wg & 7) * q + (wg >> 3);
    const int bx  = sz % nbx, by = sz / nbx;
    const int rowA0 = by * BM, rowB0 = bx * BN;

    // staging constants: thread covers 8-elem chunk (r = tid/8 within 64-row
    // group, c = tid%8); source chunk pre-swizzled so LDS stays linear.
    const int rA = tid >> 3, cA = tid & 7;
    const int cg = cA ^ (rA & 7);
    const unsigned short* srcA = Am + (size_t)(rowA0 + rA) * K + cg * 8;
    const unsigned short* srcB = Bm + (size_t)(rowB0 + rA) * K + cg * 8;
    const int dA = tid * 8;

    // per-lane LDS fragment row offsets (elems; row stride BK=64)
    int aoffm[4], boffn[4];
#pragma unroll
    for (int m = 0; m < 4; ++m) aoffm[m] = (wr * 64 + m * 16 + m16) * BK;
#pragma unroll
    for (int n = 0; n < 4; ++n) boffn[n] = (wc * 64 + n * 16 + m16) * BK;

    floatx4 acc[4][4];
#pragma unroll
    for (int m = 0; m < 4; ++m)
#pragma unroll
        for (int n = 0; n < 4; ++n)
#pragma unroll
            for (int r = 0; r < 4; ++r) acc[m][n][r] = 0.f;

    const int NT = K / BK;

    auto stageA = [&](int s, int t, int j) {   // j = 64-row group 0..3
        gld16(srcA + (size_t)(j * 64) * K + (size_t)t * BK,
              smem + s * SLOT + j * 4096 + dA);
    };
    auto stageB = [&](int s, int t, int j) {   // j = 64-row group 0..1
        gld16(srcB + (size_t)(j * 64) * K + (size_t)t * BK,
              smem + s * SLOT + ASZ + j * 4096 + dA);
    };

    // prologue: tiles 0,1 into slots 0,1 (12 loads in flight)
#pragma unroll
    for (int j = 0; j < 4; ++j) stageA(0, 0, j);
    stageB(0, 0, 0); stageB(0, 0, 1);
#pragma unroll
    for (int j = 0; j < 4; ++j) stageA(1, 1, j);
    stageB(1, 1, 0); stageB(1, 1, 1);

    int s0 = 0;
    for (int t = 0; t < NT; ++t) {
        int s2 = s0 + 2; if (s2 >= 3) s2 -= 3;
        // tile-entry: tile t's 6 loads are older than t+1's 6 -> vmcnt(6)
        // drains exactly through t (in-order retirement). Last tile: 0.
        if (t + 1 < NT) asm volatile("s_waitcnt vmcnt(6)" ::: "memory");
        else            asm volatile("s_waitcnt vmcnt(0)" ::: "memory");
        __builtin_amdgcn_s_barrier();
        __builtin_amdgcn_sched_barrier(0);

        const unsigned short* tA = smem + s0 * SLOT;
        const unsigned short* tB = tA + ASZ;
        const bool pf = (t + 2 < NT);

        short8 av[4], bv[4];

        // ---- phase 0: k-half 0 (chunks 0..3) ----
        {
            const int xo = ((0 + q4) ^ x7) * 8;
#pragma unroll
            for (int m = 0; m < 4; ++m) av[m] = *(const short8*)(tA + aoffm[m] + xo);
#pragma unroll
            for (int n = 0; n < 4; ++n) bv[n] = *(const short8*)(tB + boffn[n] + xo);
        }
        if (pf) { stageA(s2, t + 2, 0); stageA(s2, t + 2, 1); stageB(s2, t + 2, 0); }
        __builtin_amdgcn_s_barrier();
        __builtin_amdgcn_s_setprio(1);
#pragma unroll
        for (int m = 0; m < 4; ++m)
#pragma unroll
            for (int n = 0; n < 4; ++n)
                acc[m][n] = __builtin_amdgcn_mfma_f32_16x16x32_f16(
                    __builtin_bit_cast(half8, av[m]), __builtin_bit_cast(half8, bv[n]),
                    acc[m][n], 0, 0, 0);
        __builtin_amdgcn_s_setprio(0);
        __builtin_amdgcn_s_barrier();

        // ---- phase 1: k-half 1 (chunks 4..7) ----
        {
            const int xo = ((4 + q4) ^ x7) * 8;
#pragma unroll
            for (int m = 0; m < 4; ++m) av[m] = *(const short8*)(tA + aoffm[m] + xo);
#pragma unroll
            for (int n = 0; n < 4; ++n) bv[n] = *(const short8*)(tB + boffn[n] + xo);
        }
        if (pf) { stageA(s2, t + 2, 2); stageA(s2, t + 2, 3); stageB(s2, t + 2, 1); }
        __builtin_amdgcn_s_barrier();
        __builtin_amdgcn_s_setprio(1);
#pragma unroll
        for (int m = 0; m < 4; ++m)
#pragma unroll
            for (int n = 0; n < 4; ++n)
                acc[m][n] = __builtin_amdgcn_mfma_f32_16x16x32_f16(
                    __builtin_bit_cast(half8, av[m]), __builtin_bit_cast(half8, bv[n]),
                    acc[m][n], 0, 0, 0);
        __builtin_amdgcn_s_setprio(0);
        // tile-end barrier is the next tile's entry barrier

        s0 = (s0 + 1 == 3) ? 0 : s0 + 1;
    }

    // epilogue: C/D col = lane&15, row = (lane>>4)*4 + reg
#pragma unroll
    for (int m = 0; m < 4; ++m) {
#pragma unroll
        for (int n = 0; n < 4; ++n) {
            int col  = rowB0 + wc * 64 + n * 16 + m16;
            float bvl = bias[col];
#pragma unroll
            for (int r = 0; r < 4; ++r) {
                int row = rowA0 + wr * 64 + m * 16 + q4 * 4 + r;
                if (HALFOUT)
                    ((unsigned short*)Cv)[(size_t)row * N + col] = f2h(acc[m][n][r] + bvl);
                else
                    ((float*)Cv)[(size_t)row * N + col] = acc[m][n][r] + bvl;
            }
        }
    }
}

// ---------------- hierarchical quaternion prefix-product scan ----------------
// v is stored as fp16 bits (halves GEMM1 write + scan read traffic).

struct Q { float w, x, y, z; };

__device__ __forceinline__ Q qmul(Q a, Q b) {   // a later (left), b earlier
    Q r;
    r.w = a.w * b.w - a.x * b.x - a.y * b.y - a.z * b.z;
    r.x = a.w * b.x + a.x * b.w + a.y * b.z - a.z * b.y;
    r.y = a.w * b.y - a.x * b.z + a.y * b.w + a.z * b.x;
    r.z = a.w * b.z + a.x * b.y - a.y * b.x + a.z * b.w;
    return r;
}
__device__ __forceinline__ Q qnorm(Q a) {
    float nn = a.w * a.w + a.x * a.x + a.y * a.y + a.z * a.z;
    float inv = __frsqrt_rn(nn);
    Q r; r.w = a.w * inv; r.x = a.x * inv; r.y = a.y * inv; r.z = a.z * inv;
    return r;
}
__device__ __forceinline__ Q vquat(float vx, float vy, float vz) {
    float th = sqrtf(vx * vx + vy * vy + vz * vz);
    float s_, c_;
    __sincosf(th, &s_, &c_);
    float k = __fdividef(s_, th + EPSF);
    Q q; q.w = c_; q.x = k * vx; q.y = k * vy; q.z = k * vz;
    return q;
}

#define SEG  64
#define NSEG 32

// block: 256 thr = 64 h x 4 segments; grid (NSEG/4, H/64, B)
__global__ __launch_bounds__(256)
void seg_prod_kernel(const unsigned short* __restrict__ v, float* __restrict__ partials,
                     int S, int H) {
    const int b  = blockIdx.z;
    const int h  = blockIdx.y * 64 + (threadIdx.x & 63);
    const int sg = blockIdx.x * 4 + (threadIdx.x >> 6);
    const int s0 = sg * SEG;
    const size_t vstep = (size_t)3 * H;
    const unsigned short* vp = v + ((size_t)b * S + s0) * vstep + (size_t)h * 3;

    constexpr int CH = 8;
    float ax[CH], ay[CH], az[CH], bx[CH], by[CH], bz[CH];
#pragma unroll
    for (int i = 0; i < CH; ++i) {
        ax[i] = h2f(vp[i * vstep + 0]); ay[i] = h2f(vp[i * vstep + 1]); az[i] = h2f(vp[i * vstep + 2]);
    }
    Q c = {1.f, 0.f, 0.f, 0.f};
    const int NC = SEG / CH;  // 8 chunks
    for (int cc = 0; cc < NC; cc += 2) {
        if (cc + 1 < NC) {
            const unsigned short* p = vp + (size_t)(cc + 1) * CH * vstep;
#pragma unroll
            for (int i = 0; i < CH; ++i) {
                bx[i] = h2f(p[i * vstep + 0]); by[i] = h2f(p[i * vstep + 1]); bz[i] = h2f(p[i * vstep + 2]);
            }
        }
#pragma unroll
        for (int i = 0; i < CH; ++i) c = qmul(vquat(ax[i], ay[i], az[i]), c);
        if (cc + 2 < NC) {
            const unsigned short* p = vp + (size_t)(cc + 2) * CH * vstep;
#pragma unroll
            for (int i = 0; i < CH; ++i) {
                ax[i] = h2f(p[i * vstep + 0]); ay[i] = h2f(p[i * vstep + 1]); az[i] = h2f(p[i * vstep + 2]);
            }
        }
#pragma unroll
        for (int i = 0; i < CH; ++i) c = qmul(vquat(bx[i], by[i], bz[i]), c);
    }
    float4* dst = (float4*)(partials + (((size_t)b * NSEG + sg) * H + h) * 4);
    *dst = make_float4(c.w, c.x, c.y, c.z);
}

// fused scan+apply: block loads all segment partials for its 64 h into LDS,
// computes exclusive prefixes locally, applies to re-derived quats, writes
// fp16 states; sg==NSEG-1 threads emit m_final.
__global__ __launch_bounds__(256)
void apply_kernel(const unsigned short* __restrict__ v, const float* __restrict__ partials,
                  unsigned short* __restrict__ st, float* __restrict__ m_final,
                  int S, int H) {
    const int b   = blockIdx.z;
    const int hb  = blockIdx.y * 64;
    const int hl  = threadIdx.x & 63;
    const int h   = hb + hl;
    const int sg  = blockIdx.x * 4 + (threadIdx.x >> 6);
    const int s0  = sg * SEG;
    const size_t vstep = (size_t)3 * H;
    const size_t sstep = (size_t)4 * H;
    const unsigned short* vp = v + ((size_t)b * S + s0) * vstep + (size_t)h * 3;
    unsigned short* sp = st + ((size_t)b * S + s0) * sstep + (size_t)h * 4;

    __shared__ float4 lp[NSEG][64];
    for (int i = threadIdx.x; i < NSEG * 64; i += 256) {
        int s2 = i >> 6, hh = i & 63;
        lp[s2][hh] = *(const float4*)(partials + (((size_t)b * NSEG + s2) * H + hb + hh) * 4);
    }
    __syncthreads();

    Q R = {1.f, 0.f, 0.f, 0.f};
    for (int s2 = 0; s2 < sg; ++s2) {           // wave-uniform trip count
        float4 pv = lp[s2][hl];
        Q pq = {pv.x, pv.y, pv.z, pv.w};
        R = qmul(pq, R);
    }

    constexpr int CH = 8;
    float ax[CH], ay[CH], az[CH], bx[CH], by[CH], bz[CH];
#pragma unroll
    for (int i = 0; i < CH; ++i) {
        ax[i] = h2f(vp[i * vstep + 0]); ay[i] = h2f(vp[i * vstep + 1]); az[i] = h2f(vp[i * vstep + 2]);
    }
    const int NC = SEG / CH;
    for (int cc = 0; cc < NC; cc += 2) {
        if (cc + 1 < NC) {
            const unsigned short* pp = vp + (size_t)(cc + 1) * CH * vstep;
#pragma unroll
            for (int i = 0; i < CH; ++i) {
                bx[i] = h2f(pp[i * vstep + 0]); by[i] = h2f(pp[i * vstep + 1]); bz[i] = h2f(pp[i * vstep + 2]);
            }
        }
#pragma unroll
        for (int i = 0; i < CH; ++i) {
            R = qmul(vquat(ax[i], ay[i], az[i]), R);
            Q m = qnorm(R);
            ushort4 u; u.x = f2h(m.w); u.y = f2h(m.x); u.z = f2h(m.y); u.w = f2h(m.z);
            *(ushort4*)(sp + (size_t)(cc * CH + i) * sstep) = u;
        }
        if (cc + 2 < NC) {
            const unsigned short* pp = vp + (size_t)(cc + 2) * CH * vstep;
#pragma unroll
            for (int i = 0; i < CH; ++i) {
                ax[i] = h2f(pp[i * vstep + 0]); ay[i] = h2f(pp[i * vstep + 1]); az[i] = h2f(pp[i * vstep + 2]);
            }
        }
#pragma unroll
        for (int i = 0; i < CH; ++i) {
            R = qmul(vquat(bx[i], by[i], bz[i]), R);
            Q m = qnorm(R);
            ushort4 u; u.x = f2h(m.w); u.y = f2h(m.x); u.z = f2h(m.y); u.w = f2h(m.z);
            *(ushort4*)(sp + (size_t)((cc + 1) * CH + i) * sstep) = u;
        }
    }

    if (sg == NSEG - 1) {
        Q m = qnorm(R);     // inclusive product of whole chain
        float* mf = m_final + ((size_t)b * H + h) * 4;
        mf[0] = m.w; mf[1] = m.x; mf[2] = m.y; mf[3] = m.z;
    }
}

// ---------------- launch ----------------

extern "C" void kernel_launch(void* const* d_in, const int* in_sizes, int n_in,
                              void* d_out, int out_size, void* d_ws, size_t ws_size,
                              hipStream_t stream) {
    const float* x     = (const float*)d_in[0];
    const float* W_in  = (const float*)d_in[1];
    const float* b_in  = (const float*)d_in[2];
    const float* W_out = (const float*)d_in[3];
    const float* b_out = (const float*)d_in[4];
    float* out = (float*)d_out;

    const int B = 4, S = 2048, D = 1024, H = 1024;
    const int M  = B * S;    // 8192
    const int N1 = 3 * H;    // 3072
    const int K1 = D;        // 1024
    const int N2 = D;        // 1024
    const int K2 = 4 * H;    // 4096

    // ws layout (bytes):
    //   [0, 50331648)                    v     fp16 M*N1 (48 MB)
    //   [50331648, 117440512)            st    fp16 M*K2 (64 MB); x16/wi16
    //                                    overlap here (consumed by GEMM1)
    //   [117440512, 125829120)           wo16  fp16 N2*K2 (8 MB)
    char* ws = (char*)d_ws;
    unsigned short* v    = (unsigned short*)(ws);
    unsigned short* st   = (unsigned short*)(ws + 50331648u);
    unsigned short* x16  = (unsigned short*)(ws + 50331648u);
    unsigned short* wi16 = (unsigned short*)(ws + 50331648u + 16777216u);
    unsigned short* wo16 = (unsigned short*)(ws + 117440512u);

    // partials (2 MB) live in d_out — free until GEMM2 overwrites it last.
    float* partials = out;

    const int nx  = M * K1;    // 8388608
    const int nw  = N1 * K1;   // 3145728
    const int nwo = N2 * K2;   // 4194304
    const int n4  = (nx + nw + nwo) / 4;

    // 144 KB dynamic LDS needs the opt-in attribute (default cap is 64 KB)
    constexpr int LDSB = 147456;
    static int attr_done = 0;
    if (!attr_done) {
        hipFuncSetAttribute(reinterpret_cast<const void*>(&gemm8p<true>),
                            hipFuncAttributeMaxDynamicSharedMemorySize, LDSB);
        hipFuncSetAttribute(reinterpret_cast<const void*>(&gemm8p<false>),
                            hipFuncAttributeMaxDynamicSharedMemorySize, LDSB);
        attr_done = 1;
    }

    prep_kernel<<<(n4 + 255) / 256, 256, 0, stream>>>(
        (const float4*)x, (ushort4*)x16, (const float4*)W_in, (ushort4*)wi16,
        (const float4*)W_out, (ushort4*)wo16, nx / 4, nw / 4, nwo / 4);

    // v = x @ W_in^T + b_in   (fp16 out; 256x128 phase-pipelined, vmcnt(6))
    gemm8p<true><<<dim3((M / 256) * (N1 / 128)), 512, LDSB, stream>>>(
        x16, wi16, b_in, v, M, N1, K1);

    // hierarchical scan (scan fused into apply)
    dim3 sg_grid(NSEG / 4, H / 64, B);
    seg_prod_kernel<<<sg_grid, 256, 0, stream>>>(v, partials, S, H);
    apply_kernel<<<sg_grid, 256, 0, stream>>>(v, partials, st, out + (size_t)M * D, S, H);

    // out = states @ W_out^T + b_out  (fp32 out)
    gemm8p<false><<<dim3((M / 256) * (N2 / 128)), 512, LDSB, stream>>>(
        st, wo16, b_out, out, M, N2, K2);
}